// Round 8
// baseline (20263.704 us; speedup 1.0000x reference)
//
#include <hip/hip_runtime.h>
#include <math.h>

#define NBLK 256
#define TPB  512
#define KB   64           // K-tile (A staged per 64 k)
#define ATS  65           // transposed A-tile row stride (floats)
// LDS: AT = KB*ATS = 4160 f; red = 4*64*33 = 8448 f (aliased after K-loop);
// decode h2row = 2048 f (aliased). LDSF = max = 8448 floats (~33.8 KB).
#define LDSF 8448

// ---------------- static device state ----------------
#define GC 0
#define GG 512
#define RC 1024
#define RG 1056
#define AB 1088
__device__ unsigned g_sync[1120];
__device__ int g_tok[64];
__device__ int g_done[64];
__device__ __attribute__((aligned(16))) float g_hA[64 * 3584];
__device__ __attribute__((aligned(16))) float g_hB[64 * 3584];
__device__ __attribute__((aligned(16))) float g_v0h[64 * 1024];
__device__ __attribute__((aligned(16))) float g_v1a[64 * 2048];
__device__ __attribute__((aligned(16))) float g_v1b[64 * 2048];
__device__ __attribute__((aligned(16))) float g_c1x[64 * 1024];
__device__ __attribute__((aligned(16))) float g_v2a[64 * 4096];
__device__ __attribute__((aligned(16))) float g_v2b[64 * 4096];
__device__ __attribute__((aligned(16))) float g_cnd2a[64 * 2048];
__device__ __attribute__((aligned(16))) float g_cnd2b[64 * 2048];
__device__ __attribute__((aligned(16))) float g_c2x[64 * 2048];
__device__ __attribute__((aligned(16))) float g_ekg[40 * 1024];
__device__ __attribute__((aligned(16))) float g_ekc[40 * 512];

__device__ __forceinline__ float sigf(float x) { return 1.0f / (1.0f + __expf(-x)); }
__device__ __forceinline__ float tanhf_(float x) {
  float ax = fabsf(x);
  float e  = __expf(-2.0f * ax);
  float r  = (1.0f - e) / (1.0f + e);
  return copysignf(r, x);
}

// Coherent-point RMW (cross-XCD safe even relaxed; R4/R5 lesson). v=0 = fresh read.
__device__ __forceinline__ unsigned armw(unsigned* p, unsigned v) {
  return __hip_atomic_fetch_add(p, v, __ATOMIC_RELAXED, __HIP_MEMORY_SCOPE_AGENT);
}

// ---------------- A accessors (float4 over global k) ----------------
struct AccP {
  const float* p; int lda;
  __device__ __forceinline__ float4 ld(int r, int k) const {
    return *(const float4*)(p + (size_t)r * lda + k);
  }
};
struct AccH {   // hcat: k<cut -> pn, else po; both rows at hcat offset `off`
  const float* pn; const float* po; int off; int cut;
  __device__ __forceinline__ float4 ld(int r, int k) const {
    const float* b = (k < cut) ? pn : po;
    return *(const float4*)(b + (size_t)r * 3584 + off + k);
  }
};
struct AccRH0 {
  const float* v; const float* ek; const int* tk; const float* h;
  __device__ __forceinline__ float4 ld(int r, int k) const {
    int t = tk[r];
    float4 a  = *(const float4*)(v + (size_t)r * 1024 + k);
    float4 b  = *(const float4*)(ek + (size_t)t * 1024 + k);
    float4 hh = *(const float4*)(h + (size_t)r * 3584 + k);
    return make_float4(sigf(a.x + b.x) * hh.x, sigf(a.y + b.y) * hh.y,
                       sigf(a.z + b.z) * hh.z, sigf(a.w + b.w) * hh.w);
  }
};
struct AccR1 {
  const float* va; const float* vb; const float* h;   // h pre-offset (+512)
  __device__ __forceinline__ float4 ld(int r, int k) const {
    float4 a  = *(const float4*)(va + (size_t)r * 2048 + k);
    float4 b  = *(const float4*)(vb + (size_t)r * 2048 + k);
    float4 hh = *(const float4*)(h + (size_t)r * 3584 + k);
    return make_float4(sigf(a.x + b.x) * hh.x, sigf(a.y + b.y) * hh.y,
                       sigf(a.z + b.z) * hh.z, sigf(a.w + b.w) * hh.w);
  }
};
struct AccR2 {
  const float* va; const float* vb; const float* h;   // h pre-offset (+1536)
  __device__ __forceinline__ float4 ld(int r, int k) const {
    float4 a  = *(const float4*)(va + (size_t)r * 4096 + k);
    float4 b  = *(const float4*)(vb + (size_t)r * 4096 + k);
    float4 hh = *(const float4*)(h + (size_t)r * 3584 + k);
    return make_float4(sigf(a.x + b.x) * hh.x, sigf(a.y + b.y) * hh.y,
                       sigf(a.z + b.z) * hh.z, sigf(a.w + b.w) * hh.w);
  }
};
template <class Inner> struct AccOff {
  Inner in; int base;
  __device__ __forceinline__ float4 ld(int r, int k) const { return in.ld(r, base + k); }
};

// ---------------- GEMM chunk: 64 rows x 32 cols x K ----------------
// A staged transposed in LDS (b128 reads, 2-way max). W streamed from global
// with a FLAT depth-8 register ladder (16 float4 in flight per wave) that
// spans tile boundaries — hides the ~600cy L2/L3 miss latency that made R7
// latency-bound at 2 outstanding loads (R7 lesson). Static wq indices (i)
// keep the array in registers (rule #20). 8 waves k-interleaved (k≡w mod 8).
#define FMA8(J, AJ) \
  acc[J][0] = fmaf(AJ, wv0.x, acc[J][0]); acc[J][1] = fmaf(AJ, wv0.y, acc[J][1]); \
  acc[J][2] = fmaf(AJ, wv0.z, acc[J][2]); acc[J][3] = fmaf(AJ, wv0.w, acc[J][3]); \
  acc[J][4] = fmaf(AJ, wv1.x, acc[J][4]); acc[J][5] = fmaf(AJ, wv1.y, acc[J][5]); \
  acc[J][6] = fmaf(AJ, wv1.z, acc[J][6]); acc[J][7] = fmaf(AJ, wv1.w, acc[J][7]);

template <class AF, class EF>
__device__ __forceinline__ void gemm32(const AF& A, const float* __restrict__ W,
                                       const int ldw, const int c0, const int K,
                                       float* __restrict__ lds, const EF& epi) {
  float* AT = lds;
  const int tid  = threadIdx.x;
  const int w    = tid >> 6;
  const int lane = tid & 63;
  const int rgrp = lane & 15;
  const int cg   = lane >> 4;
  const int sr = tid >> 3;            // A row 0..63
  const int sk = (tid & 7) * 8;       // A k-window (8 k)

  float acc[4][8];
#pragma unroll
  for (int j = 0; j < 4; ++j)
#pragma unroll
    for (int e = 0; e < 8; ++e) acc[j][e] = 0.0f;

  // W ladder: wave w owns k = w + 8*s, s = 0..S-1. Depth-8 preload.
  const int S = K >> 3;
  const float* wp = W + (size_t)w * ldw + c0 + cg * 8;
  float4 wq0[8], wq1[8];
#pragma unroll
  for (int s = 0; s < 8; ++s) {
    wq0[s] = *(const float4*)wp;
    wq1[s] = *(const float4*)(wp + 4);
    wp += (size_t)8 * ldw;
  }

  float4 a0 = A.ld(sr, sk), a1 = A.ld(sr, sk + 4);

  const int NT = K / KB;
  for (int t = 0; t < NT; ++t) {
    __syncthreads();                  // LDS free (prev tile consumed)
    AT[(sk + 0) * ATS + sr] = a0.x;  AT[(sk + 1) * ATS + sr] = a0.y;
    AT[(sk + 2) * ATS + sr] = a0.z;  AT[(sk + 3) * ATS + sr] = a0.w;
    AT[(sk + 4) * ATS + sr] = a1.x;  AT[(sk + 5) * ATS + sr] = a1.y;
    AT[(sk + 6) * ATS + sr] = a1.z;  AT[(sk + 7) * ATS + sr] = a1.w;
    if (t + 1 < NT) {                 // next A tile prefetch
      a0 = A.ld(sr, (t + 1) * KB + sk);
      a1 = A.ld(sr, (t + 1) * KB + sk + 4);
    }
    __syncthreads();                  // tile staged
#pragma unroll
    for (int i = 0; i < 8; ++i) {     // kk = i*8 + w ; s = t*8 + i
      const float4 av = *(const float4*)&AT[(i * 8 + w) * ATS + rgrp * 4];
      const float4 wv0 = wq0[i];
      const float4 wv1 = wq1[i];
      if (t * 8 + i + 8 < S) {        // refill slot (depth 8)
        wq0[i] = *(const float4*)wp;
        wq1[i] = *(const float4*)(wp + 4);
        wp += (size_t)8 * ldw;
      }
      FMA8(0, av.x) FMA8(1, av.y) FMA8(2, av.z) FMA8(3, av.w)
    }
  }
  // ---- cross-wave tree reduction (red aliases AT) ----
  float* red = lds;
  const int rb = (rgrp * 4) * 33 + cg * 8;
#define RED_STORE(Sx) { float* rp = red + (Sx) * 2112 + rb; \
  _Pragma("unroll") for (int j = 0; j < 4; ++j) _Pragma("unroll") \
    for (int e = 0; e < 8; ++e) rp[j * 33 + e] = acc[j][e]; }
#define RED_ADD(Sx) { float* rp = red + (Sx) * 2112 + rb; \
  _Pragma("unroll") for (int j = 0; j < 4; ++j) _Pragma("unroll") \
    for (int e = 0; e < 8; ++e) acc[j][e] += rp[j * 33 + e]; }
  __syncthreads();
  if (w >= 4) RED_STORE(w - 4);
  __syncthreads();
  if (w < 4) RED_ADD(w);
  __syncthreads();
  if (w == 2 || w == 3) RED_STORE(w - 2);
  __syncthreads();
  if (w < 2) RED_ADD(w);
  __syncthreads();
  if (w == 1) RED_STORE(0);
  __syncthreads();
  if (w == 0) {
    RED_ADD(0);
#pragma unroll
    for (int j = 0; j < 4; ++j)
#pragma unroll
      for (int e = 0; e < 8; ++e)
        epi(rgrp * 4 + j, c0 + cg * 8 + e, acc[j][e]);
  }
#undef RED_STORE
#undef RED_ADD
}

// ---------------- the persistent kernel ----------------
__global__ void __launch_bounds__(TPB, 1) decoder_kernel(
    const float* __restrict__ input_vecs, const float* __restrict__ emb,
    const float* __restrict__ dense_W, const float* __restrict__ dense_b,
    const float* __restrict__ dec_W,
    const float* __restrict__ Kg0, const float* __restrict__ bg0,
    const float* __restrict__ Kc0, const float* __restrict__ bc0,
    const float* __restrict__ Kg1, const float* __restrict__ bg1,
    const float* __restrict__ Kc1, const float* __restrict__ bc1,
    const float* __restrict__ Kg2, const float* __restrict__ bg2,
    const float* __restrict__ Kc2, const float* __restrict__ bc2,
    float* __restrict__ out) {
  __shared__ float lds[LDSF];
  __shared__ float lg[40];
  const int bid = blockIdx.x;
  const int tid = threadIdx.x;
  const int grp = bid >> 4;

  unsigned epoch = 0, gbase = 0, rbase = 0;
  if (tid == 0) {
    gbase = armw(&g_sync[GG + grp * 32], 0u);
    rbase = armw(&g_sync[RG], 0u);
  }
  auto gbar = [&]() {
    __syncthreads();
    if (tid == 0) {
      __builtin_amdgcn_fence(__ATOMIC_RELEASE, "agent");     // wbl2 once
      ++epoch;
      unsigned a = armw(&g_sync[GC + grp * 32], 1u) + 1u;
      if ((a & 15u) == 0u) {
        unsigned r = armw(&g_sync[RC], 1u) + 1u;
        if ((r & 15u) == 0u) armw(&g_sync[RG], 1u);
        unsigned polls = 0;
        while ((int)(armw(&g_sync[RG], 0u) - rbase) < (int)epoch) {
          __builtin_amdgcn_s_sleep(8);
          if ((++polls & 255u) == 0u) {
            if (polls > (1u << 20)) { armw(&g_sync[AB], 1u); break; }
            if (armw(&g_sync[AB], 0u) != 0u) break;
          }
        }
        armw(&g_sync[GG + grp * 32], 1u);
      } else {
        unsigned polls = 0;
        while ((int)(armw(&g_sync[GG + grp * 32], 0u) - gbase) < (int)epoch) {
          __builtin_amdgcn_s_sleep(8);
          if ((++polls & 255u) == 0u) {
            if (polls > (1u << 20)) { armw(&g_sync[AB], 1u); break; }
            if (armw(&g_sync[AB], 0u) != 0u) break;
          }
        }
      }
    }
    __syncthreads();
    __builtin_amdgcn_fence(__ATOMIC_ACQUIRE, "agent");       // one buffer_inv/wave
  };

  // ---- init: h = input_vecs @ dense_W + b (112 chunks); emb tables; tok ----
  if (bid < 112) {
    AccP A{input_vecs, 512};
    auto epi = [&](int r, int c, float v) { g_hA[(size_t)r * 3584 + c] = v + dense_b[c]; };
    gemm32(A, dense_W, 3584, bid * 32, 512, lds, epi);
  }
  if (bid >= NBLK - 32) {
    int base = (bid - (NBLK - 32)) * 1920;
    for (int o = base + tid; o < base + 1920; o += TPB) {
      if (o < 40960) {
        int r = o >> 10, c = o & 1023;
        float s = 0.0f;
        for (int k = 0; k < 32; ++k) s += emb[r * 32 + k] * Kg0[k * 1024 + c];
        g_ekg[o] = s;
      } else {
        int o2 = o - 40960;
        int r = o2 >> 9, c = o2 & 511;
        float s = 0.0f;
        for (int k = 0; k < 32; ++k) s += emb[r * 32 + k] * Kc0[k * 512 + c];
        g_ekc[o2] = s;
      }
    }
  }
  if (bid == 128 && tid < 64) { g_tok[tid] = 39; g_done[tid] = 0; }
  gbar();

  // ---- t0 gates0h: v0h = bg0 + h0 @ Kg0h (32 chunks) ----
  if (bid < 32) {
    AccP A{g_hA, 3584};
    auto epi = [&](int r, int c, float v) { g_v0h[r * 1024 + c] = v + bg0[c]; };
    gemm32(A, Kg0 + 32 * 1024, 1024, bid * 32, 512, lds, epi);
  }
  gbar();

  for (int t = 0; t < 50; ++t) {
    const float* hOld = (t & 1) ? g_hB : g_hA;
    float*       hNew = (t & 1) ? g_hA : g_hB;

    // Ph2: cand0 -> h0' (16 chunks, K=512)
    if (bid < 16) {
      AccRH0 A{g_v0h, g_ekg, g_tok, hOld};
      auto epi = [&](int r, int c, float v) {
        int tk = g_tok[r];
        float cx = g_ekc[tk * 512 + c] + bc0[c];
        float z  = sigf(g_v0h[r * 1024 + 512 + c] + g_ekg[tk * 1024 + 512 + c]);
        float ho = hOld[(size_t)r * 3584 + c];
        hNew[(size_t)r * 3584 + c] = z * ho + (1.0f - z) * tanhf_(v + cx);
      };
      gemm32(A, Kc0 + 32 * 512, 512, bid * 32, 512, lds, epi);
    }
    gbar();

    // Ph3: gates1 split-K x2 (64 chunks x 2, K=768 each) + c1x (32 chunks, K=512)
    if (bid < 128) {
      const int half = bid >> 6, ch = bid & 63;
      AccOff<AccH> A{{hNew, hOld, 0, 512}, half * 768};
      float* dst = half ? g_v1b : g_v1a;
      if (half == 0) {
        auto epi = [&](int r, int c, float v) { dst[r * 2048 + c] = v + bg1[c]; };
        gemm32(A, Kg1, 2048, ch * 32, 768, lds, epi);
      } else {
        auto epi = [&](int r, int c, float v) { dst[r * 2048 + c] = v; };
        gemm32(A, Kg1 + (size_t)768 * 2048, 2048, ch * 32, 768, lds, epi);
      }
    } else if (bid < 160) {
      AccP A{hNew, 3584};
      auto epi = [&](int r, int c, float v) { g_c1x[r * 1024 + c] = v + bc1[c]; };
      gemm32(A, Kc1, 1024, (bid - 128) * 32, 512, lds, epi);
    }
    gbar();

    // Ph4: cand1 -> h1' (32 chunks, K=1024)
    if (bid < 32) {
      AccR1 A{g_v1a, g_v1b, hOld + 512};
      auto epi = [&](int r, int c, float v) {
        float z  = sigf(g_v1a[r * 2048 + 1024 + c] + g_v1b[r * 2048 + 1024 + c]);
        float cx = g_c1x[r * 1024 + c];
        float ho = hOld[(size_t)r * 3584 + 512 + c];
        hNew[(size_t)r * 3584 + 512 + c] = z * ho + (1.0f - z) * tanhf_(v + cx);
      };
      gemm32(A, Kc1 + (size_t)512 * 1024, 1024, bid * 32, 1024, lds, epi);
    }
    gbar();

    // Ph5: gates2 split-K x2 (128 chunks x 2, K=1536 each)
    {
      const int half = bid >> 7, ch = bid & 127;
      AccOff<AccH> A{{hNew, hOld, 512, 1024}, half * 1536};
      if (half == 0) {
        auto epi = [&](int r, int c, float v) { g_v2a[(size_t)r * 4096 + c] = v + bg2[c]; };
        gemm32(A, Kg2, 4096, ch * 32, 1536, lds, epi);
      } else {
        auto epi = [&](int r, int c, float v) { g_v2b[(size_t)r * 4096 + c] = v; };
        gemm32(A, Kg2 + (size_t)1536 * 4096, 4096, ch * 32, 1536, lds, epi);
      }
    }
    gbar();

    // Ph6: cand2 split-K x2, RAW partials (64 chunks x 2, K=1024)
    //      + c2x (64 chunks, K=1024)   [combine deferred to Ph7]
    if (bid < 128) {
      const int half = bid >> 6, ch = bid & 63;
      AccOff<AccR2> A{{g_v2a, g_v2b, hOld + 1536}, half * 1024};
      float* dst = half ? g_cnd2b : g_cnd2a;
      auto epi = [&](int r, int c, float v) { dst[r * 2048 + c] = v; };
      gemm32(A, Kc2 + (size_t)(1024 + half * 1024) * 2048, 2048, ch * 32, 1024, lds, epi);
    } else if (bid < 192) {
      AccP A{hNew + 512, 3584};
      auto epi = [&](int r, int c, float v) { g_c2x[r * 2048 + c] = v + bc2[c]; };
      gemm32(A, Kc2, 2048, (bid - 128) * 32, 1024, lds, epi);
    }
    gbar();

    // Ph7: decode+combine h2' (blocks 0..63) || gates0h(t+1) (blocks 64..95)
    if (bid < 64) {
      const int b = bid;
      float* h2row = lds;              // 2048 floats
      {
        const int c = tid * 4;
        float4 va = *(const float4*)&g_v2a[(size_t)b * 4096 + 2048 + c];
        float4 vb = *(const float4*)&g_v2b[(size_t)b * 4096 + 2048 + c];
        float4 ca = *(const float4*)&g_cnd2a[b * 2048 + c];
        float4 cb = *(const float4*)&g_cnd2b[b * 2048 + c];
        float4 cx = *(const float4*)&g_c2x[b * 2048 + c];
        float4 ho = *(const float4*)&hOld[(size_t)b * 3584 + 1536 + c];
        float4 r;
#define GRU2(comp) { float z = sigf(va.comp + vb.comp); \
        r.comp = z * ho.comp + (1.0f - z) * tanhf_(ca.comp + cb.comp + cx.comp); }
        GRU2(x) GRU2(y) GRU2(z) GRU2(w)
#undef GRU2
        *(float4*)&hNew[(size_t)b * 3584 + 1536 + c] = r;
        *(float4*)&h2row[c] = r;
      }
      __syncthreads();
      float acc = 0.0f;
      if (tid < 320) {
        const int v = tid >> 3, p = tid & 7;
        for (int i = 0; i < 64; ++i) {
          const int k = p * 4 + i * 32;
          float4 h = *(const float4*)&h2row[k];
          acc += h.x * dec_W[k * 40 + v] + h.y * dec_W[(k + 1) * 40 + v] +
                 h.z * dec_W[(k + 2) * 40 + v] + h.w * dec_W[(k + 3) * 40 + v];
        }
        acc += __shfl_xor(acc, 4);
        acc += __shfl_xor(acc, 2);
        acc += __shfl_xor(acc, 1);
        if (p == 0) lg[v] = acc;
      }
      __syncthreads();
      if (tid == 0) {
        int idx = 0; float best = lg[0];
        for (int v = 1; v < 40; ++v) { if (lg[v] > best) { best = lg[v]; idx = v; } }
        const int dn = g_done[b];
        out[b * 50 + t] = dn ? 0.0f : (float)idx;
        float* olg = out + 3200 + (size_t)(b * 50 + t) * 40;
        for (int v = 0; v < 40; ++v) olg[v] = dn ? 0.0f : lg[v];
        if (!dn) { g_tok[b] = idx; if (idx == 0) g_done[b] = 1; }
      }
    } else if (bid < 96) {
      AccP A{hNew, 3584};             // reads h0' (all-new)
      auto epi = [&](int r, int c, float v) { g_v0h[r * 1024 + c] = v + bg0[c]; };
      gemm32(A, Kg0 + 32 * 1024, 1024, (bid - 64) * 32, 512, lds, epi);
    }
    gbar();
  }
}

extern "C" void kernel_launch(void* const* d_in, const int* in_sizes, int n_in,
                              void* d_out, int out_size, void* d_ws, size_t ws_size,
                              hipStream_t stream) {
  (void)in_sizes; (void)n_in; (void)d_ws; (void)ws_size; (void)out_size;
  void* p0  = d_in[0];  void* p1  = d_in[1];  void* p2  = d_in[2];
  void* p3  = d_in[3];  void* p4  = d_in[4];  void* p5  = d_in[5];
  void* p6  = d_in[6];  void* p7  = d_in[7];  void* p8  = d_in[8];
  void* p9  = d_in[9];  void* p10 = d_in[10]; void* p11 = d_in[11];
  void* p12 = d_in[12]; void* p13 = d_in[13]; void* p14 = d_in[14];
  void* p15 = d_in[15]; void* p16 = d_in[16]; void* po  = d_out;
  void* args[] = {&p0, &p1, &p2, &p3, &p4, &p5, &p6, &p7, &p8,
                  &p9, &p10, &p11, &p12, &p13, &p14, &p15, &p16, &po};
  hipLaunchCooperativeKernel((const void*)decoder_kernel, dim3(NBLK), dim3(TPB),
                             args, 0, stream);
}